// Round 1
// 305.941 us; speedup vs baseline: 1.0807x; 1.0807x over previous
//
#include <hip/hip_runtime.h>

typedef __bf16 bf16;
typedef __bf16 bf16x4 __attribute__((ext_vector_type(4)));
typedef __bf16 bf16x8 __attribute__((ext_vector_type(8)));
typedef float  f32x4  __attribute__((ext_vector_type(4)));

#define MFMA16(A_, B_, C_) __builtin_amdgcn_mfma_f32_16x16x32_bf16((A_), (B_), (C_), 0, 0, 0)

// ---- constants ----
#define BB 4
#define TT 2048
#define CC 1024
#define HH 16
#define DD 64
#define MM (BB * TT)         // 8192
#define N_QKV (3 * CC)       // 3072
#define LDSS 72              // attention LDS row stride: 144 B -> every row 16B-aligned
#define BSTRIDE 36           // tier-C sB row stride
// 1/sqrt(D) * log2(e): p = exp(s/8) computed as exp2(s * QSCALE2)
#define QSCALE2 0.18033688f

static __device__ __forceinline__ void store_lds8(bf16* p, bf16x8 v) {
  bf16x4 lo, hi;
#pragma unroll
  for (int i = 0; i < 4; i++) { lo[i] = v[i]; hi[i] = v[i + 4]; }
  *(bf16x4*)p = lo;
  *(bf16x4*)(p + 4) = hi;
}

static __device__ __forceinline__ bf16x8 load_lds8(const bf16* p) {
  bf16x4 lo = *(const bf16x4*)p;
  bf16x4 hi = *(const bf16x4*)(p + 4);
  bf16x8 v;
#pragma unroll
  for (int i = 0; i < 4; i++) { v[i] = lo[i]; v[i + 4] = hi[i]; }
  return v;
}

// async global->LDS, 16 B per lane; LDS dest = wave-uniform base + lane*16
static __device__ __forceinline__ void async_cp16(const bf16* g, bf16* l) {
  __builtin_amdgcn_global_load_lds(
      (const __attribute__((address_space(1))) void*)g,
      (__attribute__((address_space(3))) void*)l, 16, 0, 0);
}

// -------------------- dtype sniff --------------------
__global__ __launch_bounds__(256) void sniff_k(const unsigned short* __restrict__ u,
                                               int* __restrict__ flag) {
  __shared__ int s;
  if (threadIdx.x == 0) s = 0;
  __syncthreads();
  int c = 0;
  for (int i = threadIdx.x; i < 65536; i += 256)
    if ((u[i] & 0x7F80u) == 0x7F80u) c = 1;
  if (c) atomicOr(&s, 1);
  __syncthreads();
  if (threadIdx.x == 0) *flag = s;   // 1 = fp32 world, 0 = bf16 world
}

// -------------------- x -> bf16 convert (or copy-through), with src offset ---
__global__ __launch_bounds__(256) void cvt_k(const void* __restrict__ in,
                                             bf16* __restrict__ out,
                                             const int* __restrict__ flag,
                                             size_t off) {
  const int fl = *flag;
  const size_t i = ((size_t)blockIdx.x * 256 + threadIdx.x) * 8;
  if (fl) {
    f32x4 a = *(const f32x4*)((const float*)in + off + i);
    f32x4 b = *(const f32x4*)((const float*)in + off + i + 4);
    bf16x8 o;
#pragma unroll
    for (int j = 0; j < 4; j++) { o[j] = (bf16)a[j]; o[4 + j] = (bf16)b[j]; }
    *(bf16x8*)(out + i) = o;
  } else {
    *(bf16x8*)(out + i) = *(const bf16x8*)((const bf16*)in + off + i);
  }
}

// ------------- transpose + convert-to-bf16: out[c*R+r] = (bf16)in[r*C+c] -----
__global__ __launch_bounds__(256) void transpose_k(const void* __restrict__ in,
                                                   bf16* __restrict__ out,
                                                   int R, int C,
                                                   const int* __restrict__ flag) {
  __shared__ bf16 tile[32][33];
  const int fl = *flag;
  const int c0 = blockIdx.x * 32, r0 = blockIdx.y * 32;
  const int tx = threadIdx.x & 31, ty = threadIdx.x >> 5;
#pragma unroll
  for (int i = ty; i < 32; i += 8) {
    const size_t idx = (size_t)(r0 + i) * C + c0 + tx;
    tile[i][tx] = fl ? (bf16)((const float*)in)[idx] : ((const bf16*)in)[idx];
  }
  __syncthreads();
#pragma unroll
  for (int i = ty; i < 32; i += 8)
    out[(size_t)(c0 + i) * R + r0 + tx] = tile[tx][i];
}

// ----- GEMM, all-bf16, global_load_lds staging (m97 ladder step 3) -----------
template <int EPI>
__global__ __launch_bounds__(256) void gemm_lds(const bf16* __restrict__ A,
                                                const bf16* __restrict__ Bt,
                                                const void* __restrict__ biasv,
                                                void* __restrict__ Cv,
                                                const int* __restrict__ flag,
                                                size_t aoff, size_t coff,
                                                int M, int N, int K,
                                                int lda, int ldc) {
  const int fl = *flag;
  __shared__ __align__(16) bf16 sA[128 * 32];
  __shared__ __align__(16) bf16 sB[128 * 32];
  const int tid = threadIdx.x;
  const int lane = tid & 63, wave = tid >> 6;
  const int quad = lane >> 4, l15 = lane & 15;
  const int wr = wave >> 1, wc = wave & 1;
  const int m0 = blockIdx.x * 128, n0 = blockIdx.y * 128;
  const int grow = lane >> 2;         // 0..15
  const int gcol = (lane & 3) * 8;    // 0,8,16,24

  f32x4 acc[4][4];
#pragma unroll
  for (int i = 0; i < 4; i++)
#pragma unroll
    for (int j = 0; j < 4; j++) {
      f32x4 z = {0.f, 0.f, 0.f, 0.f};
      acc[i][j] = z;
    }

  const bf16* Ag = A + aoff + (size_t)(m0 + wave * 32 + grow) * lda + gcol;
  const bf16* Bg = Bt + (size_t)(n0 + wave * 32 + grow) * K + gcol;
  bf16* sAw = sA + wave * 32 * 32;
  bf16* sBw = sB + wave * 32 * 32;

  for (int k0 = 0; k0 < K; k0 += 32) {
    __syncthreads();
    async_cp16(Ag, sAw);
    async_cp16(Ag + (size_t)16 * lda, sAw + 16 * 32);
    async_cp16(Bg, sBw);
    async_cp16(Bg + (size_t)16 * K, sBw + 16 * 32);
    Ag += 32;
    Bg += 32;
    __syncthreads();

    bf16x8 af[4], bfr[4];
#pragma unroll
    for (int mi = 0; mi < 4; mi++)
      af[mi] = *(const bf16x8*)(sA + (wr * 64 + mi * 16 + l15) * 32 + quad * 8);
#pragma unroll
    for (int ni = 0; ni < 4; ni++)
      bfr[ni] = *(const bf16x8*)(sB + (wc * 64 + ni * 16 + l15) * 32 + quad * 8);
#pragma unroll
    for (int mi = 0; mi < 4; mi++)
#pragma unroll
      for (int ni = 0; ni < 4; ni++)
        acc[mi][ni] = MFMA16(af[mi], bfr[ni], acc[mi][ni]);
  }

#pragma unroll
  for (int mi = 0; mi < 4; mi++) {
#pragma unroll
    for (int r = 0; r < 4; r++) {
      const int m = m0 + wr * 64 + mi * 16 + quad * 4 + r;
#pragma unroll
      for (int ni = 0; ni < 4; ni++) {
        const int n = n0 + wc * 64 + ni * 16 + l15;
        float v = acc[mi][ni][r];
        const size_t idx = coff + (size_t)m * ldc + n;
        if (EPI == 1) {
          v += fl ? ((const float*)biasv)[n] : (float)((const bf16*)biasv)[n];
          if (fl) ((float*)Cv)[idx] = v;
          else    ((bf16*)Cv)[idx] = (bf16)v;
        } else {
          ((bf16*)Cv)[idx] = (bf16)v;
        }
      }
    }
  }
}

// ----- GEMM (B pre-transposed, register staging; A may be fp32) --------------
template <int EPI, bool AF>
__global__ __launch_bounds__(256) void gemm_bt(const void* __restrict__ Av,
                                               const bf16* __restrict__ Bt,
                                               const void* __restrict__ biasv,
                                               void* __restrict__ Cv,
                                               const int* __restrict__ flag,
                                               size_t aoff, size_t coff,
                                               int M, int N, int K,
                                               int lda, int ldc) {
  const int fl = *flag;
  const bool af32 = AF && (fl != 0);
  __shared__ __align__(16) bf16 sA[128 * 32];
  __shared__ __align__(16) bf16 sB[128 * 32];
  const int tid = threadIdx.x;
  const int lane = tid & 63, wave = tid >> 6;
  const int quad = lane >> 4, l15 = lane & 15;
  const int wr = wave >> 1, wc = wave & 1;
  const int m0 = blockIdx.x * 128, n0 = blockIdx.y * 128;
  const int srow = tid >> 2;          // 0..63
  const int scol = (tid & 3) * 8;     // 0,8,16,24

  f32x4 acc[4][4];
#pragma unroll
  for (int i = 0; i < 4; i++)
#pragma unroll
    for (int j = 0; j < 4; j++) {
      f32x4 z = {0.f, 0.f, 0.f, 0.f};
      acc[i][j] = z;
    }

  const size_t abase0 = aoff + (size_t)(m0 + srow) * lda + scol;
  const size_t abase1 = abase0 + (size_t)64 * lda;
  const bf16* Bg0 = Bt + (size_t)(n0 + srow) * K + scol;
  const bf16* Bg1 = Bg0 + (size_t)64 * K;

  for (int k0 = 0; k0 < K; k0 += 32) {
    bf16x8 a0, a1;
    if (af32) {
      const float* Af = (const float*)Av;
      f32x4 p00 = *(const f32x4*)(Af + abase0 + k0);
      f32x4 p01 = *(const f32x4*)(Af + abase0 + k0 + 4);
      f32x4 p10 = *(const f32x4*)(Af + abase1 + k0);
      f32x4 p11 = *(const f32x4*)(Af + abase1 + k0 + 4);
#pragma unroll
      for (int i = 0; i < 4; i++) {
        a0[i] = (bf16)p00[i]; a0[i + 4] = (bf16)p01[i];
        a1[i] = (bf16)p10[i]; a1[i + 4] = (bf16)p11[i];
      }
    } else {
      const bf16* Ab = (const bf16*)Av;
      a0 = *(const bf16x8*)(Ab + abase0 + k0);
      a1 = *(const bf16x8*)(Ab + abase1 + k0);
    }
    bf16x8 b0 = *(const bf16x8*)(Bg0 + k0);
    bf16x8 b1 = *(const bf16x8*)(Bg1 + k0);
    __syncthreads();
    *(bf16x8*)(sA + srow * 32 + scol) = a0;
    *(bf16x8*)(sA + (64 + srow) * 32 + scol) = a1;
    *(bf16x8*)(sB + srow * 32 + scol) = b0;
    *(bf16x8*)(sB + (64 + srow) * 32 + scol) = b1;
    __syncthreads();

    bf16x8 af[4], bfr[4];
#pragma unroll
    for (int mi = 0; mi < 4; mi++)
      af[mi] = *(const bf16x8*)(sA + (wr * 64 + mi * 16 + l15) * 32 + quad * 8);
#pragma unroll
    for (int ni = 0; ni < 4; ni++)
      bfr[ni] = *(const bf16x8*)(sB + (wc * 64 + ni * 16 + l15) * 32 + quad * 8);
#pragma unroll
    for (int mi = 0; mi < 4; mi++)
#pragma unroll
      for (int ni = 0; ni < 4; ni++)
        acc[mi][ni] = MFMA16(af[mi], bfr[ni], acc[mi][ni]);
  }

#pragma unroll
  for (int mi = 0; mi < 4; mi++) {
#pragma unroll
    for (int r = 0; r < 4; r++) {
      const int m = m0 + wr * 64 + mi * 16 + quad * 4 + r;
#pragma unroll
      for (int ni = 0; ni < 4; ni++) {
        const int n = n0 + wc * 64 + ni * 16 + l15;
        float v = acc[mi][ni][r];
        const size_t idx = coff + (size_t)m * ldc + n;
        if (EPI == 1) {
          v += fl ? ((const float*)biasv)[n] : (float)((const bf16*)biasv)[n];
          if (fl) ((float*)Cv)[idx] = v;
          else    ((bf16*)Cv)[idx] = (bf16)v;
        } else {
          ((bf16*)Cv)[idx] = (bf16)v;
        }
      }
    }
  }
}

// ----- tier-C GEMM (W row-major, in-kernel transpose staging) ----------------
template <int EPI, bool AF, bool WF>
__global__ __launch_bounds__(256) void gemm_nt(const void* __restrict__ Av,
                                               const void* __restrict__ Wv,
                                               const void* __restrict__ biasv,
                                               void* __restrict__ Cv,
                                               const int* __restrict__ flag,
                                               size_t aoff, size_t coff,
                                               int M, int N, int K,
                                               int lda, int ldc) {
  const int fl = *flag;
  const bool af32 = AF && (fl != 0);
  const bool wf32 = WF && (fl != 0);
  __shared__ __align__(16) bf16 sA[128 * 32];
  __shared__ __align__(16) bf16 sB[128 * BSTRIDE];
  const int tid = threadIdx.x;
  const int lane = tid & 63, wave = tid >> 6;
  const int quad = lane >> 4, l15 = lane & 15;
  const int wr = wave >> 1, wc = wave & 1;
  const int m0 = blockIdx.x * 128, n0 = blockIdx.y * 128;
  const int arow = tid >> 2, acol = (tid & 3) * 8;
  const int wk = tid >> 3, wn = (tid & 7) * 16;

  f32x4 acc[4][4];
#pragma unroll
  for (int i = 0; i < 4; i++)
#pragma unroll
    for (int j = 0; j < 4; j++) {
      f32x4 z = {0.f, 0.f, 0.f, 0.f};
      acc[i][j] = z;
    }

  const size_t abase0 = aoff + (size_t)(m0 + arow) * lda + acol;
  const size_t abase1 = abase0 + (size_t)64 * lda;

  for (int k0 = 0; k0 < K; k0 += 32) {
    bf16x8 a0, a1;
    if (af32) {
      const float* Af = (const float*)Av;
      f32x4 p00 = *(const f32x4*)(Af + abase0 + k0);
      f32x4 p01 = *(const f32x4*)(Af + abase0 + k0 + 4);
      f32x4 p10 = *(const f32x4*)(Af + abase1 + k0);
      f32x4 p11 = *(const f32x4*)(Af + abase1 + k0 + 4);
#pragma unroll
      for (int i = 0; i < 4; i++) {
        a0[i] = (bf16)p00[i]; a0[i + 4] = (bf16)p01[i];
        a1[i] = (bf16)p10[i]; a1[i + 4] = (bf16)p11[i];
      }
    } else {
      const bf16* Ab = (const bf16*)Av;
      a0 = *(const bf16x8*)(Ab + abase0 + k0);
      a1 = *(const bf16x8*)(Ab + abase1 + k0);
    }
    bf16 wreg[16];
    const size_t wbase = (size_t)(k0 + wk) * N + n0 + wn;
    if (wf32) {
      const float* Wf = (const float*)Wv;
      f32x4 q0 = *(const f32x4*)(Wf + wbase);
      f32x4 q1 = *(const f32x4*)(Wf + wbase + 4);
      f32x4 q2 = *(const f32x4*)(Wf + wbase + 8);
      f32x4 q3 = *(const f32x4*)(Wf + wbase + 12);
#pragma unroll
      for (int i = 0; i < 4; i++) {
        wreg[i] = (bf16)q0[i];      wreg[4 + i] = (bf16)q1[i];
        wreg[8 + i] = (bf16)q2[i];  wreg[12 + i] = (bf16)q3[i];
      }
    } else {
      const bf16* Wb = (const bf16*)Wv;
      bf16x8 w0 = *(const bf16x8*)(Wb + wbase);
      bf16x8 w1 = *(const bf16x8*)(Wb + wbase + 8);
#pragma unroll
      for (int i = 0; i < 8; i++) { wreg[i] = w0[i]; wreg[8 + i] = w1[i]; }
    }
    __syncthreads();
    *(bf16x8*)(sA + arow * 32 + acol) = a0;
    *(bf16x8*)(sA + (64 + arow) * 32 + acol) = a1;
#pragma unroll
    for (int i = 0; i < 16; i++)
      sB[(wn + i) * BSTRIDE + wk] = wreg[i];
    __syncthreads();

    bf16x8 af[4], bfr[4];
#pragma unroll
    for (int mi = 0; mi < 4; mi++)
      af[mi] = *(const bf16x8*)(sA + (wr * 64 + mi * 16 + l15) * 32 + quad * 8);
#pragma unroll
    for (int ni = 0; ni < 4; ni++)
      bfr[ni] = load_lds8(sB + (wc * 64 + ni * 16 + l15) * BSTRIDE + quad * 8);
#pragma unroll
    for (int mi = 0; mi < 4; mi++)
#pragma unroll
      for (int ni = 0; ni < 4; ni++)
        acc[mi][ni] = MFMA16(af[mi], bfr[ni], acc[mi][ni]);
  }

#pragma unroll
  for (int mi = 0; mi < 4; mi++) {
#pragma unroll
    for (int r = 0; r < 4; r++) {
      const int m = m0 + wr * 64 + mi * 16 + quad * 4 + r;
#pragma unroll
      for (int ni = 0; ni < 4; ni++) {
        const int n = n0 + wc * 64 + ni * 16 + l15;
        float v = acc[mi][ni][r];
        const size_t idx = coff + (size_t)m * ldc + n;
        if (EPI == 1) {
          v += fl ? ((const float*)biasv)[n] : (float)((const bf16*)biasv)[n];
          if (fl) ((float*)Cv)[idx] = v;
          else    ((bf16*)Cv)[idx] = (bf16)v;
        } else {
          ((bf16*)Cv)[idx] = (bf16)v;
        }
      }
    }
  }
}

// -------------------- flash attention, max-free softmax ----------------------
// grid: (nb*H, 16), block 256. blockIdx.y selects the q-tile, mapped
// heavy-first (qt = 15 - y) so long-running diagonal-distant tiles launch
// early and the scheduler packs the short ones behind them. One q-tile per
// block -> 1024 blocks (Tier A) = 4 blocks/CU (vs 2 with the old pairing),
// doubling waves/SIMD to overlap the exp/LDS chain of one wave with MFMA of
// another. p = exp2(s*QSCALE2) (scale folded into staged Q); row sums l via
// MFMA against a ones-B-fragment. LDSS=72 -> all LDS vector ops are b128.
__global__ __launch_bounds__(256) void attn_k(bf16* __restrict__ qkv) {
  __shared__ __align__(16) bf16 sQ[128 * LDSS];   // wave regions reused for P
  __shared__ __align__(16) bf16 sK[64 * LDSS];
  __shared__ __align__(16) bf16 sVt[64 * LDSS];   // [dim][key]

  const int tid = threadIdx.x;
  const int lane = tid & 63, wave = tid >> 6;
  const int quad = lane >> 4, l15 = lane & 15;
  const int bh = blockIdx.x;
  bf16* base = qkv + (size_t)(bh >> 4) * TT * N_QKV + (bh & 15) * DD;
  const bf16* Qp = base;
  const bf16* Kp = base + CC;
  const bf16* Vp = base + 2 * CC;

  const int krow = tid >> 2;          // 0..63
  const int kcol = (tid & 3) * 16;    // 0,16,32,48
  const int vkey = tid & 31;          // 0..31
  const int vcol = (tid >> 5) * 8;    // 0..56

  bf16x8 ones;
  {
    const bf16 o = (l15 == 0) ? (bf16)1.0f : (bf16)0.0f;
#pragma unroll
    for (int i = 0; i < 8; i++) ones[i] = o;
  }

  const int qt = 15 - (int)blockIdx.y;   // heavy tiles dispatched first
  const int q0 = qt * 128;

  // ---- stage Q (pre-scaled by QSCALE2) ----
#pragma unroll
  for (int p = 0; p < 2; p++) {
    const int r = p * 64 + krow;
    const bf16* src = Qp + (size_t)(q0 + r) * N_QKV + kcol;
    bf16x8 v0 = *(const bf16x8*)src;
    bf16x8 v1 = *(const bf16x8*)(src + 8);
#pragma unroll
    for (int i = 0; i < 8; i++) {
      v0[i] = (bf16)((float)v0[i] * QSCALE2);
      v1[i] = (bf16)((float)v1[i] * QSCALE2);
    }
    *(bf16x8*)(sQ + r * LDSS + kcol) = v0;
    *(bf16x8*)(sQ + r * LDSS + kcol + 8) = v1;
  }

  // prefetch K/V tile 0
  bf16x8 kr0, kr1, vr0, vr1;
  {
    const bf16* kp = Kp + (size_t)krow * N_QKV + kcol;
    kr0 = *(const bf16x8*)kp;
    kr1 = *(const bf16x8*)(kp + 8);
    vr0 = *(const bf16x8*)(Vp + (size_t)vkey * N_QKV + vcol);
    vr1 = *(const bf16x8*)(Vp + (size_t)(32 + vkey) * N_QKV + vcol);
  }
  __syncthreads();

  bf16x8 aq[2][2];
#pragma unroll
  for (int mi = 0; mi < 2; mi++) {
    const bf16* qp = sQ + (size_t)(wave * 32 + mi * 16 + l15) * LDSS + quad * 8;
    aq[mi][0] = *(const bf16x8*)qp;
    aq[mi][1] = *(const bf16x8*)(qp + 32);
  }

  f32x4 Oacc[2][4];
  f32x4 lacc[2];
#pragma unroll
  for (int mi = 0; mi < 2; mi++) {
    f32x4 z = {0.f, 0.f, 0.f, 0.f};
    lacc[mi] = z;
#pragma unroll
    for (int nt = 0; nt < 4; nt++) Oacc[mi][nt] = z;
  }

  const int jmax = q0 + 64;
  const int wave_row0 = q0 + wave * 32;
  bf16* sP = sQ + (size_t)(wave * 32) * LDSS;   // wave-private P region

  for (int j0 = 0; j0 <= jmax; j0 += 64) {
    __syncthreads();
    *(bf16x8*)(sK + krow * LDSS + kcol) = kr0;
    *(bf16x8*)(sK + krow * LDSS + kcol + 8) = kr1;
#pragma unroll
    for (int i = 0; i < 8; i++) {
      sVt[(vcol + i) * LDSS + vkey] = vr0[i];
      sVt[(vcol + i) * LDSS + 32 + vkey] = vr1[i];
    }
    __syncthreads();

    if (j0 + 64 <= jmax) {          // prefetch next tile (overlaps compute)
      const bf16* kp = Kp + (size_t)(j0 + 64 + krow) * N_QKV + kcol;
      kr0 = *(const bf16x8*)kp;
      kr1 = *(const bf16x8*)(kp + 8);
      vr0 = *(const bf16x8*)(Vp + (size_t)(j0 + 64 + vkey) * N_QKV + vcol);
      vr1 = *(const bf16x8*)(Vp + (size_t)(j0 + 96 + vkey) * N_QKV + vcol);
    }

    if (j0 <= wave_row0 + 31) {     // skip fully-masked tiles (wave-uniform)
      // ---- S = (Q*QSCALE2) K^T ----
      f32x4 S[2][4];
#pragma unroll
      for (int nt = 0; nt < 4; nt++) {
        const bf16* kp = sK + (size_t)(nt * 16 + l15) * LDSS + quad * 8;
        bf16x8 bk0 = *(const bf16x8*)kp;
        bf16x8 bk1 = *(const bf16x8*)(kp + 32);
#pragma unroll
        for (int mi = 0; mi < 2; mi++) {
          f32x4 acc = {0.f, 0.f, 0.f, 0.f};
          acc = MFMA16(aq[mi][0], bk0, acc);
          acc = MFMA16(aq[mi][1], bk1, acc);
          S[mi][nt] = acc;
        }
      }

      // ---- p = exp2(s), predicated causal mask (unified loop) ----
      const bool needmask = (j0 + 63 > wave_row0);
#pragma unroll
      for (int mi = 0; mi < 2; mi++)
#pragma unroll
        for (int nt = 0; nt < 4; nt++) {
          const int kc = j0 + nt * 16 + l15;
#pragma unroll
          for (int r = 0; r < 4; r++) {
            float e = __builtin_amdgcn_exp2f(S[mi][nt][r]);
            if (needmask && kc > wave_row0 + mi * 16 + quad * 4 + r) e = 0.f;
            sP[(size_t)(mi * 16 + quad * 4 + r) * LDSS + nt * 16 + l15] =
                (bf16)e;
          }
        }

      // ---- O += P V ; l += P 1 ----
      bf16x8 ap[2][2];
#pragma unroll
      for (int mi = 0; mi < 2; mi++) {
        const bf16* pp = sP + (size_t)(mi * 16 + l15) * LDSS + quad * 8;
        ap[mi][0] = *(const bf16x8*)pp;
        ap[mi][1] = *(const bf16x8*)(pp + 32);
        lacc[mi] = MFMA16(ap[mi][0], ones, lacc[mi]);
        lacc[mi] = MFMA16(ap[mi][1], ones, lacc[mi]);
      }
#pragma unroll
      for (int nt = 0; nt < 4; nt++) {
        const bf16* vp = sVt + (size_t)(nt * 16 + l15) * LDSS + quad * 8;
        bf16x8 bv0 = *(const bf16x8*)vp;
        bf16x8 bv1 = *(const bf16x8*)(vp + 32);
#pragma unroll
        for (int mi = 0; mi < 2; mi++) {
          Oacc[mi][nt] = MFMA16(ap[mi][0], bv0, Oacc[mi][nt]);
          Oacc[mi][nt] = MFMA16(ap[mi][1], bv1, Oacc[mi][nt]);
        }
      }
    }
  }

  // ---- epilogue ----
#pragma unroll
  for (int mi = 0; mi < 2; mi++)
#pragma unroll
    for (int r = 0; r < 4; r++) {
      const float lv = __shfl(lacc[mi][r], lane & 48, 64);
      const float invl = 1.0f / lv;
      const int t = q0 + wave * 32 + mi * 16 + quad * 4 + r;
#pragma unroll
      for (int nt = 0; nt < 4; nt++)
        base[(size_t)t * N_QKV + nt * 16 + l15] =
            (bf16)(Oacc[mi][nt][r] * invl);
    }
}

// -------------------- launch --------------------
extern "C" void kernel_launch(void* const* d_in, const int* in_sizes, int n_in,
                              void* d_out, int out_size, void* d_ws, size_t ws_size,
                              hipStream_t stream) {
  const void* x = d_in[0];       // [8192,1024] fp32 or bf16
  const void* w_qkv = d_in[1];   // [1024,3072]
  const void* w_out = d_in[2];   // [1024,1024]
  const void* b_out = d_in[3];   // [1024]

  int* flag = (int*)d_ws;
  char* p = (char*)d_ws + 256;
  bf16* wqkvT = (bf16*)p;                          // [3072,1024]  6 MB
  bf16* woutT = wqkvT + (size_t)N_QKV * CC;        // [1024,1024]  2 MB

  const size_t wT_bytes = ((size_t)N_QKV * CC + (size_t)CC * CC) * 2;  // 8 MB
  const size_t qkv_bytes = (size_t)MM * N_QKV * 2;                     // 48 MB
  const size_t need_A = 256 + wT_bytes + qkv_bytes;                    // 56.25 MB
  const size_t need_B = 256 + wT_bytes + (size_t)TT * N_QKV * 2;

  sniff_k<<<1, 256, 0, stream>>>((const unsigned short*)x, flag);

  if (ws_size >= need_A) {
    // ---- Tier A: fused; qkv GEMM path adapts to available slack ----
    bf16* qkv = woutT + (size_t)CC * CC;
    bf16* xb = qkv + (size_t)MM * N_QKV;
    const size_t slack = ws_size - need_A;

    transpose_k<<<dim3(N_QKV / 32, CC / 32), 256, 0, stream>>>(w_qkv, wqkvT, CC, N_QKV, flag);
    transpose_k<<<dim3(CC / 32, CC / 32), 256, 0, stream>>>(w_out, woutT, CC, CC, flag);

    const size_t full_xb = (size_t)MM * CC * 2;    // 16 MB
    const size_t half_xb = full_xb / 2;            // 8 MB
    if (slack >= full_xb) {
      // single pre-convert, one lds-direct GEMM
      cvt_k<<<(MM * CC) / 2048, 256, 0, stream>>>(x, xb, flag, 0);
      gemm_lds<0><<<dim3(MM / 128, N_QKV / 128), 256, 0, stream>>>(
          xb, wqkvT, nullptr, qkv, flag, 0, 0, MM, N_QKV, CC, CC, N_QKV);
    } else if (slack >= half_xb) {
      // two 4096-row chunks
      for (int m0 = 0; m0 < MM; m0 += 4096) {
        cvt_k<<<(4096 * CC) / 2048, 256, 0, stream>>>(x, xb, flag, (size_t)m0 * CC);
        gemm_lds<0><<<dim3(4096 / 128, N_QKV / 128), 256, 0, stream>>>(
            xb, wqkvT, nullptr, qkv, flag, 0, (size_t)m0 * N_QKV,
            4096, N_QKV, CC, CC, N_QKV);
      }
    } else {
      // no room: fp32-A register-staged GEMM
      gemm_bt<0, true><<<dim3(MM / 128, N_QKV / 128), 256, 0, stream>>>(
          x, wqkvT, nullptr, qkv, flag, 0, 0, MM, N_QKV, CC, CC, N_QKV);
    }

    attn_k<<<dim3(BB * HH, 16), 256, 0, stream>>>(qkv);

    gemm_lds<1><<<dim3(MM / 128, CC / 128), 256, 0, stream>>>(
        qkv, woutT, b_out, d_out, flag, 0, 0, MM, CC, CC, N_QKV, CC);
  } else if (ws_size >= need_B) {
    // ---- Tier B: per-batch, pre-transposed weights ----
    bf16* qkv = woutT + (size_t)CC * CC;
    transpose_k<<<dim3(N_QKV / 32, CC / 32), 256, 0, stream>>>(w_qkv, wqkvT, CC, N_QKV, flag);
    transpose_k<<<dim3(CC / 32, CC / 32), 256, 0, stream>>>(w_out, woutT, CC, CC, flag);
    for (int b = 0; b < BB; b++) {
      const size_t xoff = (size_t)b * TT * CC;
      gemm_bt<0, true><<<dim3(TT / 128, N_QKV / 128), 256, 0, stream>>>(
          x, wqkvT, nullptr, qkv, flag, xoff, 0, TT, N_QKV, CC, CC, N_QKV);
      attn_k<<<dim3(HH, 16), 256, 0, stream>>>(qkv);
      gemm_lds<1><<<dim3(TT / 128, CC / 128), 256, 0, stream>>>(
          qkv, woutT, b_out, d_out, flag, 0, xoff, TT, CC, CC, N_QKV, CC);
    }
  } else {
    // ---- Tier C: minimal ws ----
    bf16* qkvb = (bf16*)p;
    for (int b = 0; b < BB; b++) {
      const size_t xoff = (size_t)b * TT * CC;
      gemm_nt<0, true, true><<<dim3(TT / 128, N_QKV / 128), 256, 0, stream>>>(
          x, w_qkv, nullptr, qkvb, flag, xoff, 0, TT, N_QKV, CC, CC, N_QKV);
      attn_k<<<dim3(HH, 16), 256, 0, stream>>>(qkvb);
      gemm_nt<1, false, true><<<dim3(TT / 128, CC / 128), 256, 0, stream>>>(
          qkvb, w_out, b_out, d_out, flag, 0, xoff, TT, CC, CC, N_QKV, CC);
    }
  }
}